// Round 1
// baseline (47.296 us; speedup 1.0000x reference)
//
#include <hip/hip_runtime.h>
#include <hip/hip_bf16.h>

#define BATCH_N 2097152

__device__ __forceinline__ float fsig(float x) {
    // sigmoid(x) = 1 / (1 + e^-x); fast exp (v_exp_f32) + fast div (v_rcp_f32)
    return __fdividef(1.0f, 1.0f + __expf(-x));
}

__device__ __forceinline__ float ftanh(float x) {
    // tanh(x) = 2*sigmoid(2x) - 1 ; saturates correctly for |x| large
    return __builtin_fmaf(2.0f, fsig(2.0f * x), -1.0f);
}

__global__ __launch_bounds__(256) void lstm_fc_kernel(
    const float4* __restrict__ x4,     // [B] float4 (SEQ=4, INPUT=1 contiguous)
    const float*  __restrict__ W_ih,   // [8]  ([4H,1])
    const float*  __restrict__ W_hh,   // [8,2]
    const float*  __restrict__ b_ih,   // [8]
    const float*  __restrict__ b_hh,   // [8]
    const float*  __restrict__ W_fc,   // [1,2]
    const float*  __restrict__ b_fc,   // [1]
    float* __restrict__ out,           // [B]
    int B)
{
    // Load tiny weights once per thread (uniform addresses -> cache hits),
    // amortized over the grid-stride loop.
    float wih[8], whh0[8], whh1[8], bs[8];
#pragma unroll
    for (int g = 0; g < 8; ++g) {
        wih[g]  = W_ih[g];
        whh0[g] = W_hh[2 * g];
        whh1[g] = W_hh[2 * g + 1];
        bs[g]   = b_ih[g] + b_hh[g];
    }
    const float wfc0 = W_fc[0], wfc1 = W_fc[1], bfc = b_fc[0];

    const int stride = gridDim.x * blockDim.x;
    for (int idx = blockIdx.x * blockDim.x + threadIdx.x; idx < B; idx += stride) {
        const float4 xv = x4[idx];
        const float xs[4] = {xv.x, xv.y, xv.z, xv.w};

        float h0 = 0.f, h1 = 0.f, c0 = 0.f, c1 = 0.f;
#pragma unroll
        for (int t = 0; t < 4; ++t) {
            float gates[8];
#pragma unroll
            for (int g = 0; g < 8; ++g) {
                gates[g] = __builtin_fmaf(wih[g], xs[t],
                           __builtin_fmaf(whh0[g], h0,
                           __builtin_fmaf(whh1[g], h1, bs[g])));
            }
            // gate order [i, f, g, o], each of size H=2
            const float i0 = fsig(gates[0]), i1 = fsig(gates[1]);
            const float f0 = fsig(gates[2]), f1 = fsig(gates[3]);
            const float g0 = ftanh(gates[4]), g1 = ftanh(gates[5]);
            const float o0 = fsig(gates[6]), o1 = fsig(gates[7]);
            c0 = __builtin_fmaf(f0, c0, i0 * g0);
            c1 = __builtin_fmaf(f1, c1, i1 * g1);
            h0 = o0 * ftanh(c0);
            h1 = o1 * ftanh(c1);
        }
        out[idx] = __builtin_fmaf(wfc0, h0, __builtin_fmaf(wfc1, h1, bfc));
    }
}

extern "C" void kernel_launch(void* const* d_in, const int* in_sizes, int n_in,
                              void* d_out, int out_size, void* d_ws, size_t ws_size,
                              hipStream_t stream) {
    const float4* x4   = (const float4*)d_in[0];
    const float*  W_ih = (const float*)d_in[1];
    const float*  W_hh = (const float*)d_in[2];
    const float*  b_ih = (const float*)d_in[3];
    const float*  b_hh = (const float*)d_in[4];
    const float*  W_fc = (const float*)d_in[5];
    const float*  b_fc = (const float*)d_in[6];
    float* out = (float*)d_out;

    const int B = out_size;              // BATCH elements, one output each
    const int block = 256;
    int grid = 2048;                     // grid-stride; 4 elements/thread at B=2M
    lstm_fc_kernel<<<grid, block, 0, stream>>>(x4, W_ih, W_hh, b_ih, b_hh,
                                               W_fc, b_fc, out, B);
}

// Round 2
// 22.454 us; speedup vs baseline: 2.1064x; 2.1064x over previous
//
#include <hip/hip_runtime.h>
#include <hip/hip_bf16.h>

// Sigmoid LUT over x in [-8, 8], 256 cells of width 1/16.
// tab[i]     = sigma(-8 + i/16)
// tab[256+i] = sigma(-8 + (i+1)/16) - sigma(-8 + i/16)   (slope for lerp)
// Lookup index space: y = 16*x + 128, clamped to [0, 255.999].
__device__ __forceinline__ float lut_sig(const float* __restrict__ tab, float y) {
    float yc = __builtin_amdgcn_fmed3f(y, 0.0f, 255.999f);
    int   iy = (int)yc;
    float fy = yc - (float)iy;
    // tab[iy] and tab[256+iy]: constant 1024B apart -> one ds_read2_b32
    return fmaf(tab[256 + iy], fy, tab[iy]);
}

__global__ __launch_bounds__(256) void lstm_fc_lut(
    const float4* __restrict__ x4,     // [B] float4 (SEQ=4, INPUT=1)
    const float*  __restrict__ W_ih,   // [8]
    const float*  __restrict__ W_hh,   // [8,2]
    const float*  __restrict__ b_ih,   // [8]
    const float*  __restrict__ b_hh,   // [8]
    const float*  __restrict__ W_fc,   // [1,2]
    const float*  __restrict__ b_fc,   // [1]
    float* __restrict__ out,           // [B]
    int B)
{
    __shared__ float tab[512];
    {
        const int t = threadIdx.x;          // exactly 256 threads
        const float x0 = -8.0f + (float)t * 0.0625f;
        const float s0 = __fdividef(1.0f, 1.0f + __expf(-x0));
        const float s1 = __fdividef(1.0f, 1.0f + __expf(-(x0 + 0.0625f)));
        tab[t]       = s0;
        tab[256 + t] = s1 - s0;
    }
    __syncthreads();

    // Pre-scaled weights: gate index space y = s*gate + 128 folded into weights.
    // Gate order [i,f,g,o] x H=2: 0,1=i  2,3=f  4,5=g  6,7=o.
    // s = 16 for sigmoid gates, 32 for g (tanh(x) = 2*sigma(2x)-1).
    float ws[8], w0[8], w1[8], bb[8];
#pragma unroll
    for (int g = 0; g < 8; ++g) {
        const float s = (g == 4 || g == 5) ? 32.0f : 16.0f;
        ws[g] = s * W_ih[g];
        w0[g] = s * W_hh[2 * g];
        w1[g] = s * W_hh[2 * g + 1];
        bb[g] = fmaf(s, b_ih[g] + b_hh[g], 128.0f);
    }
    const float wfc0 = W_fc[0], wfc1 = W_fc[1], bfc = b_fc[0];

    const int half = B >> 1;
    const int tid = blockIdx.x * blockDim.x + threadIdx.x;
    if (tid >= half) return;

    // Two independent elements per thread for ILP on the serial chain.
    const float4 xa = x4[tid];
    const float4 xb = x4[tid + half];
    float xs[2][4] = {{xa.x, xa.y, xa.z, xa.w}, {xb.x, xb.y, xb.z, xb.w}};

    float h0[2], h1[2], d0[2], d1[2];   // d = 2*c (so tanh(c) = 2*lut(16*d+128)-1)

    // ---- t = 0 (h = c = 0): gates = ws*x + bb; f-gate unused ----
#pragma unroll
    for (int e = 0; e < 2; ++e) {
        float y[8];
#pragma unroll
        for (int g = 0; g < 8; ++g) y[g] = fmaf(ws[g], xs[e][0], bb[g]);
        {   // unit 0
            const float si = lut_sig(tab, y[0]);
            const float sg = lut_sig(tab, y[4]);
            const float so = lut_sig(tab, y[6]);
            const float u  = fmaf(4.0f, sg, -2.0f);      // = 2*tanh(g)
            d0[e] = si * u;
            const float sd = lut_sig(tab, fmaf(d0[e], 16.0f, 128.0f));
            h0[e] = so * fmaf(2.0f, sd, -1.0f);
        }
        {   // unit 1
            const float si = lut_sig(tab, y[1]);
            const float sg = lut_sig(tab, y[5]);
            const float so = lut_sig(tab, y[7]);
            const float u  = fmaf(4.0f, sg, -2.0f);
            d1[e] = si * u;
            const float sd = lut_sig(tab, fmaf(d1[e], 16.0f, 128.0f));
            h1[e] = so * fmaf(2.0f, sd, -1.0f);
        }
    }

    // ---- t = 1..3 ----
#pragma unroll
    for (int t = 1; t < 4; ++t) {
#pragma unroll
        for (int e = 0; e < 2; ++e) {
            float y[8];
#pragma unroll
            for (int g = 0; g < 8; ++g)
                y[g] = fmaf(ws[g], xs[e][t],
                       fmaf(w0[g], h0[e],
                       fmaf(w1[g], h1[e], bb[g])));
            {   // unit 0
                const float si = lut_sig(tab, y[0]);
                const float sf = lut_sig(tab, y[2]);
                const float sg = lut_sig(tab, y[4]);
                const float so = lut_sig(tab, y[6]);
                const float u  = fmaf(4.0f, sg, -2.0f);
                d0[e] = fmaf(sf, d0[e], si * u);
                const float sd = lut_sig(tab, fmaf(d0[e], 16.0f, 128.0f));
                h0[e] = so * fmaf(2.0f, sd, -1.0f);
            }
            {   // unit 1
                const float si = lut_sig(tab, y[1]);
                const float sf = lut_sig(tab, y[3]);
                const float sg = lut_sig(tab, y[5]);
                const float so = lut_sig(tab, y[7]);
                const float u  = fmaf(4.0f, sg, -2.0f);
                d1[e] = fmaf(sf, d1[e], si * u);
                const float sd = lut_sig(tab, fmaf(d1[e], 16.0f, 128.0f));
                h1[e] = so * fmaf(2.0f, sd, -1.0f);
            }
        }
    }

    out[tid]        = fmaf(wfc0, h0[0], fmaf(wfc1, h1[0], bfc));
    out[tid + half] = fmaf(wfc0, h0[1], fmaf(wfc1, h1[1], bfc));
}

extern "C" void kernel_launch(void* const* d_in, const int* in_sizes, int n_in,
                              void* d_out, int out_size, void* d_ws, size_t ws_size,
                              hipStream_t stream) {
    const float4* x4   = (const float4*)d_in[0];
    const float*  W_ih = (const float*)d_in[1];
    const float*  W_hh = (const float*)d_in[2];
    const float*  b_ih = (const float*)d_in[3];
    const float*  b_hh = (const float*)d_in[4];
    const float*  W_fc = (const float*)d_in[5];
    const float*  b_fc = (const float*)d_in[6];
    float* out = (float*)d_out;

    const int B = out_size;                 // 2,097,152
    const int half = B >> 1;
    const int block = 256;
    const int grid = (half + block - 1) / block;   // 4096 blocks, 2 elems/thread
    lstm_fc_lut<<<grid, block, 0, stream>>>(x4, W_ih, W_hh, b_ih, b_hh,
                                            W_fc, b_fc, out, B);
}